// Round 6
// baseline (226.096 us; speedup 1.0000x reference)
//
#include <hip/hip_runtime.h>
#include <hip/hip_bf16.h>
#include <math.h>

#define EPSF 1e-5f

typedef float f32x4 __attribute__((ext_vector_type(4)));
typedef short short8 __attribute__((ext_vector_type(8)));
typedef short short4v __attribute__((ext_vector_type(4)));

static __device__ __forceinline__ unsigned short f2bf(float f) {
    unsigned u = __float_as_uint(f);
    u = (u + 0x7FFF + ((u >> 16) & 1)) >> 16;
    return (unsigned short)u;
}

static __device__ __forceinline__ unsigned packbf2(float a, float b) {
    __hip_bfloat162 t = __float22bfloat162_rn(float2{a, b});
    union { __hip_bfloat162 v; unsigned u; } cv;
    cv.v = t;
    return cv.u;
}

// XOR-swizzle: spreads 8-byte granules of a row across banks; keeps 16B pairs.
static __device__ __forceinline__ int swz(int r) { return ((r ^ (r >> 2)) & 7) << 1; }

// ---------------------------------------------------------------------------
// Depthwise 3x3 conv (SAME), vectorized: each thread computes a 4x8 tile.
// ---------------------------------------------------------------------------
template<bool BN>
__global__ __launch_bounds__(256) void dwconv_k(
    const float* __restrict__ X, const float* __restrict__ DW,
    const float* __restrict__ g, const float* __restrict__ be,
    const float* __restrict__ mn, const float* __restrict__ vr,
    float* __restrict__ Out)
{
    int tid = threadIdx.x;
    int plane = blockIdx.x * 2 + (tid >> 7);
    int c = plane & 255;
    float inv = 1.f, ad = 0.f;
    if (BN) {
        inv = g[c] * rsqrtf(vr[c] + EPSF);
        ad  = be[c] - mn[c] * inv;
    }
    float w[9];
#pragma unroll
    for (int i = 0; i < 9; ++i) w[i] = DW[c * 9 + i];
    const float* Xb = X + (size_t)plane * 4096;
    float* Ob = Out + (size_t)plane * 4096;
    int u  = tid & 127;
    int y0 = (u >> 3) * 4;
    int x0 = (u & 7) * 8;

    float r[6][16];
#pragma unroll
    for (int rr = 0; rr < 6; ++rr) {
        int yy = y0 + rr - 1;
        bool rv = (unsigned)yy < 64u;
#pragma unroll
        for (int gq = 0; gq < 4; ++gq) {
            int xx = x0 - 4 + gq * 4;
            f32x4 v = {0.f, 0.f, 0.f, 0.f};
            if (rv && (unsigned)xx < 64u) {
                v = *(const f32x4*)&Xb[yy * 64 + xx];
                if (BN) {
#pragma unroll
                    for (int j = 0; j < 4; ++j) v[j] = v[j] * inv + ad;
                }
            }
            r[rr][gq * 4 + 0] = v[0]; r[rr][gq * 4 + 1] = v[1];
            r[rr][gq * 4 + 2] = v[2]; r[rr][gq * 4 + 3] = v[3];
        }
    }

#pragma unroll
    for (int j = 0; j < 4; ++j) {
        float acc[8] = {};
#pragma unroll
        for (int ky = 0; ky < 3; ++ky) {
#pragma unroll
            for (int kx = 0; kx < 3; ++kx) {
                float ww = w[ky * 3 + kx];
#pragma unroll
                for (int p = 0; p < 8; ++p)
                    acc[p] += ww * r[j + ky][3 + p + kx];
            }
        }
        f32x4 lo = {acc[0], acc[1], acc[2], acc[3]};
        f32x4 hi = {acc[4], acc[5], acc[6], acc[7]};
        *(f32x4*)&Ob[(y0 + j) * 64 + x0]     = lo;
        *(f32x4*)&Ob[(y0 + j) * 64 + x0 + 4] = hi;
    }
}

// ---------------------------------------------------------------------------
// Bilinear align_corners=True resize 64x64 -> 16x16 per channel plane.
// ---------------------------------------------------------------------------
__global__ __launch_bounds__(256) void interp_k(
    const float* __restrict__ T, float* __restrict__ R)
{
    int bc = blockIdx.x;
    const float* Tb = T + (size_t)bc * 4096;
    int p  = threadIdx.x;
    int oy = p >> 4, ox = p & 15;
    const float st = 63.0f / 15.0f;
    float fy = oy * st, fx = ox * st;
    int y0 = (int)floorf(fy); int y1 = min(y0 + 1, 63); float wy = fy - (float)y0;
    int x0 = (int)floorf(fx); int x1 = min(x0 + 1, 63); float wx = fx - (float)x0;
    float v00 = Tb[y0 * 64 + x0], v01 = Tb[y0 * 64 + x1];
    float v10 = Tb[y1 * 64 + x0], v11 = Tb[y1 * 64 + x1];
    R[(size_t)bc * 256 + p] =
        (1.f - wy) * ((1.f - wx) * v00 + wx * v01) +
        wy         * ((1.f - wx) * v10 + wx * v11);
}

// ---------------------------------------------------------------------------
// Relative-position bias precompute: btab[h][qcell][key] (f32, 2 MB).
// qcell = ay*16+ax (reduced coords of query), key = by*16+bx.
// ---------------------------------------------------------------------------
__global__ __launch_bounds__(256) void bias_k(
    const float* __restrict__ rel, float* __restrict__ btab)
{
    int idx = blockIdx.x * 256 + threadIdx.x;  // 524288 total
    int h   = idx >> 16;
    int qc  = (idx >> 8) & 255;
    int key = idx & 255;
    int ay = qc >> 4, ax = qc & 15, by = key >> 4, bx = key & 15;
    int t = (ay - by + 15) * 31 + (ax - bx + 15);
    btab[idx] = rel[t * 8 + h];
}

// ---------------------------------------------------------------------------
// bf16 MFMA GEMM: Out[b][n][m] = sum_k W[n][k] * A[b][k][m]  (K=256 fixed)
// MODE 0: plain. MODE 1: += X. MODE 2: A'=relu(bn(A)) (channel=k), += X.
// OB: write output as bf16 (ushort) instead of f32.
// ---------------------------------------------------------------------------
template<int MODE, bool OB>
__global__ __launch_bounds__(256) void mgemm_k(
    const float* __restrict__ A, const float* __restrict__ W,
    float* __restrict__ Out, const float* __restrict__ X,
    const float* __restrict__ g, const float* __restrict__ be,
    const float* __restrict__ mn, const float* __restrict__ vr,
    int M, int Ntot)
{
    __shared__ short Ws[128 * 256];
    __shared__ short As[128 * 64];
    int b = blockIdx.z, m0 = blockIdx.x * 128, n0 = blockIdx.y * 128;
    int tid = threadIdx.x;
    const float* Ab = A + (size_t)b * 256 * M;

#pragma unroll
    for (int it = 0; it < 32; ++it) {
        int idx = it * 256 + tid;
        int n = idx >> 6, kq = idx & 63;
        f32x4 w4 = *(const f32x4*)&W[(size_t)(n0 + n) * 256 + kq * 4];
        short4v pk = { (short)f2bf(w4[0]), (short)f2bf(w4[1]),
                       (short)f2bf(w4[2]), (short)f2bf(w4[3]) };
        *(short4v*)&Ws[n * 256 + ((kq ^ swz(n)) << 2)] = pk;
    }

    int mg = tid & 31, kg = tid >> 5;
    f32x4 rg[8];
    auto load_tile = [&](int k0) {
#pragma unroll
        for (int half = 0; half < 2; ++half) {
#pragma unroll
            for (int i = 0; i < 4; ++i) {
                int c = k0 + kg * 4 + half * 32 + i;
                f32x4 v = *(const f32x4*)&Ab[(size_t)c * M + m0 + mg * 4];
                if (MODE == 2) {
                    float iv = g[c] * rsqrtf(vr[c] + EPSF);
                    float ad = be[c] - mn[c] * iv;
#pragma unroll
                    for (int j = 0; j < 4; ++j) v[j] = fmaxf(v[j] * iv + ad, 0.f);
                }
                rg[half * 4 + i] = v;
            }
        }
    };
    load_tile(0);

    int w = tid >> 6, lane = tid & 63;
    int wm = w & 1, wn = w >> 1;
    int lg = lane >> 4, lc = lane & 15;
    f32x4 acc[4][4] = {};

    for (int k0 = 0; k0 < 256; k0 += 64) {
        __syncthreads();
#pragma unroll
        for (int half = 0; half < 2; ++half) {
#pragma unroll
            for (int j = 0; j < 4; ++j) {
                int m = mg * 4 + j;
                short4v pk = { (short)f2bf(rg[half * 4 + 0][j]), (short)f2bf(rg[half * 4 + 1][j]),
                               (short)f2bf(rg[half * 4 + 2][j]), (short)f2bf(rg[half * 4 + 3][j]) };
                *(short4v*)&As[m * 64 + (((kg + half * 8) ^ swz(m)) << 2)] = pk;
            }
        }
        __syncthreads();
        if (k0 < 192) load_tile(k0 + 64);
#pragma unroll
        for (int ksl = 0; ksl < 2; ++ksl) {
            short8 wf[4], af[4];
            int gk = (k0 + ksl * 32 + lg * 8) >> 2;
            int ga = (ksl * 32 + lg * 8) >> 2;
#pragma unroll
            for (int nt = 0; nt < 4; ++nt) {
                int n = wn * 64 + nt * 16 + lc;
                wf[nt] = *(const short8*)&Ws[n * 256 + ((gk ^ swz(n)) << 2)];
            }
#pragma unroll
            for (int mt = 0; mt < 4; ++mt) {
                int m = wm * 64 + mt * 16 + lc;
                af[mt] = *(const short8*)&As[m * 64 + ((ga ^ swz(m)) << 2)];
            }
#pragma unroll
            for (int nt = 0; nt < 4; ++nt)
#pragma unroll
                for (int mt = 0; mt < 4; ++mt)
                    acc[nt][mt] = __builtin_amdgcn_mfma_f32_16x16x32_bf16(
                        wf[nt], af[mt], acc[nt][mt], 0, 0, 0);
        }
    }

    size_t ob = (size_t)b * Ntot * M;
#pragma unroll
    for (int nt = 0; nt < 4; ++nt) {
#pragma unroll
        for (int mt = 0; mt < 4; ++mt) {
#pragma unroll
            for (int reg = 0; reg < 4; ++reg) {
                int n = n0 + wn * 64 + nt * 16 + lg * 4 + reg;
                int m = m0 + wm * 64 + mt * 16 + lc;
                size_t addr = ob + (size_t)n * M + m;
                float v = acc[nt][mt][reg];
                if (MODE >= 1) v += X[addr];
                if (OB) ((unsigned short*)Out)[addr] = f2bf(v);
                else    Out[addr] = v;
            }
        }
    }
}

// ---------------------------------------------------------------------------
// MFMA attention, swapped-QK layout: S[key][qrow].
// Bias comes in as mfma C-init from global btab (L2). No rels LDS, no P LDS.
// Q: bf16 [B,256ch,4096] (ch=d*8+h), KV: bf16 [B,512,256], O: f32.
// grid (16, H, B), 256 threads = 4 waves, each wave 64 q-rows (4 m-tiles).
// ---------------------------------------------------------------------------
__global__ __launch_bounds__(256, 4) void attn_mfma_k(
    const unsigned short* __restrict__ Q, const unsigned short* __restrict__ KV,
    const float* __restrict__ btab, float* __restrict__ O)
{
    __shared__ unsigned short Ks[256 * 40];   // [key][dim], pad 40 (20.0 KB)
    __shared__ unsigned short Vt[32 * 264];   // [dim][key], pad 264 (16.9 KB)

    int b = blockIdx.z, h = blockIdx.y, chunk = blockIdx.x;
    int tid = threadIdx.x;
    const unsigned short* kvb = KV + (size_t)b * 512 * 256;

    // stage K: Ks[key][dim] (pairs of dims -> b32 writes)
#pragma unroll
    for (int it = 0; it < 16; ++it) {
        int idx = it * 256 + tid;
        int r = idx & 255, d = (idx >> 8) * 2;
        unsigned pk = (unsigned)kvb[(size_t)(d * 8 + h) * 256 + r]
                    | ((unsigned)kvb[(size_t)((d + 1) * 8 + h) * 256 + r] << 16);
        *(unsigned*)&Ks[r * 40 + d] = pk;
    }
    // stage V transposed: Vt[dim][key] (4 consecutive keys -> b64 writes)
#pragma unroll
    for (int it = 0; it < 8; ++it) {
        int idx = it * 256 + tid;
        int d = idx >> 6, k4 = (idx & 63) * 4;
        ushort4 v4 = *(const ushort4*)&kvb[(size_t)(256 + d * 8 + h) * 256 + k4];
        *(ushort4*)&Vt[d * 264 + k4] = v4;
    }
    __syncthreads();

    int w = tid >> 6, lane = tid & 63;
    int lg = lane >> 4, lc = lane & 15;

    const float SCALE = 0.17677669529663687f;  // 32^-0.5
    const unsigned short* Qb = Q + (size_t)b * 256 * 4096;
    float* Ob = O + (size_t)b * 256 * 4096;
    const float* bt = btab + (size_t)h * 256 * 256;
    int rw = chunk * 256 + w * 64;

    int s1 = ((lg & 1) << 5) + lc;
    int s2 = s1 + 16;
    bool useOdd = (lg >> 1) != 0;

    for (int mt = 0; mt < 4; ++mt) {
        int rbase = rw + mt * 16;
        int r_a = rbase + lc;
        int qc = ((r_a >> 8) << 4) | ((r_a >> 2) & 15);
        const float* bq = bt + (size_t)qc * 256 + lg * 4;

        // bias into accumulator (C-init)
        f32x4 sacc[16];
#pragma unroll
        for (int kt = 0; kt < 16; ++kt)
            sacc[kt] = *(const f32x4*)&bq[kt * 16];

        // Q B-fragment: col = qrow (lc), k = dim lg*8+j
        short8 qf;
#pragma unroll
        for (int j = 0; j < 8; ++j)
            qf[j] = (short)Qb[(size_t)((lg * 8 + j) * 8 + h) * 4096 + r_a];

        // QK^T swapped with bias C-init: sacc = K·Q + bias
#pragma unroll
        for (int kt = 0; kt < 16; ++kt) {
            short8 kf = *(const short8*)&Ks[(kt * 16 + lc) * 40 + lg * 8];
            sacc[kt] = __builtin_amdgcn_mfma_f32_16x16x32_bf16(kf, qf, sacc[kt], 0, 0, 0);
        }

        // raw row max (row = q-row = lc, across lg,kt,reg)
        float mx = -1e30f;
#pragma unroll
        for (int kt = 0; kt < 16; ++kt)
            mx = fmaxf(mx, fmaxf(fmaxf(sacc[kt][0], sacc[kt][1]),
                                 fmaxf(sacc[kt][2], sacc[kt][3])));
        mx = fmaxf(mx, __shfl_xor(mx, 16));
        mx = fmaxf(mx, __shfl_xor(mx, 32));
        float nms = -mx * SCALE;

        // fused exp + pack + exchange + PV
        float ls = 0.f;
        f32x4 o0 = {0.f, 0.f, 0.f, 0.f}, o1 = {0.f, 0.f, 0.f, 0.f};
#pragma unroll
        for (int ks = 0; ks < 8; ++ks) {
            float pa0 = __expf(fmaf(sacc[2 * ks][0],     SCALE, nms));
            float pa1 = __expf(fmaf(sacc[2 * ks][1],     SCALE, nms));
            float pa2 = __expf(fmaf(sacc[2 * ks][2],     SCALE, nms));
            float pa3 = __expf(fmaf(sacc[2 * ks][3],     SCALE, nms));
            float pb0 = __expf(fmaf(sacc[2 * ks + 1][0], SCALE, nms));
            float pb1 = __expf(fmaf(sacc[2 * ks + 1][1], SCALE, nms));
            float pb2 = __expf(fmaf(sacc[2 * ks + 1][2], SCALE, nms));
            float pb3 = __expf(fmaf(sacc[2 * ks + 1][3], SCALE, nms));
            ls += ((pa0 + pa1) + (pa2 + pa3)) + ((pb0 + pb1) + (pb2 + pb3));
            unsigned pl0 = packbf2(pa0, pa1), ph0 = packbf2(pa2, pa3);
            unsigned pl1 = packbf2(pb0, pb1), ph1 = packbf2(pb2, pb3);

            int eA = __shfl((int)pl0, s1), oA = __shfl((int)pl1, s1);
            int eB = __shfl((int)ph0, s1), oB = __shfl((int)ph1, s1);
            int eC = __shfl((int)pl0, s2), oC = __shfl((int)pl1, s2);
            int eD = __shfl((int)ph0, s2), oD = __shfl((int)ph1, s2);
            int4 pi = { useOdd ? oA : eA, useOdd ? oB : eB,
                        useOdd ? oC : eC, useOdd ? oD : eD };
            short8 pf = *(short8*)&pi;
            short8 v0 = *(const short8*)&Vt[lc * 264 + ks * 32 + lg * 8];
            short8 v1 = *(const short8*)&Vt[(16 + lc) * 264 + ks * 32 + lg * 8];
            o0 = __builtin_amdgcn_mfma_f32_16x16x32_bf16(v0, pf, o0, 0, 0, 0);
            o1 = __builtin_amdgcn_mfma_f32_16x16x32_bf16(v1, pf, o1, 0, 0, 0);
        }
        ls += __shfl_xor(ls, 16);
        ls += __shfl_xor(ls, 32);

        // epilogue: lane holds dims d=lg*4+reg (o0) / 16+lg*4+reg (o1), qrow=lc
        float rl = 1.f / ls;
#pragma unroll
        for (int reg = 0; reg < 4; ++reg) {
            int d0 = lg * 4 + reg;
            Ob[(size_t)(d0 * 8 + h) * 4096 + rbase + lc]        = o0[reg] * rl;
            Ob[(size_t)((16 + d0) * 8 + h) * 4096 + rbase + lc] = o1[reg] * rl;
        }
    }
}

// ---------------------------------------------------------------------------
extern "C" void kernel_launch(void* const* d_in, const int* in_sizes, int n_in,
                              void* d_out, int out_size, void* d_ws, size_t ws_size,
                              hipStream_t stream)
{
    const float* x       = (const float*)d_in[0];
    const float* bn1_g   = (const float*)d_in[1];
    const float* bn1_b   = (const float*)d_in[2];
    const float* bn1_m   = (const float*)d_in[3];
    const float* bn1_v   = (const float*)d_in[4];
    const float* qkv_dw  = (const float*)d_in[5];
    const float* qkv_pw  = (const float*)d_in[6];
    const float* out_dw  = (const float*)d_in[7];
    const float* out_pw  = (const float*)d_in[8];
    const float* rel     = (const float*)d_in[9];
    const float* bn2_g   = (const float*)d_in[10];
    const float* bn2_b   = (const float*)d_in[11];
    const float* bn2_m   = (const float*)d_in[12];
    const float* bn2_v   = (const float*)d_in[13];
    const float* mlp_w   = (const float*)d_in[14];
    float* out = (float*)d_out;

    float* ws = (float*)d_ws;
    float* t    = ws;                            // BUF0: t / o / a (f32)
    float* q    = ws + (size_t)8 * 1024 * 1024;  // BUF1: q(bf16) / t2(f32)
    float* tr   = ws + (size_t)16 * 1024 * 1024;
    float* kv   = tr + 524288;                   // bf16 region (2 MB used)
    float* btab = kv + 1048576;                  // f32 bias table (2 MB)
    float* o   = t;
    float* t2  = q;
    float* a   = t;

    // 0. bias table precompute
    bias_k<<<dim3(2048), 256, 0, stream>>>(rel, btab);

    // 1. t = dwconv3(bn1(x))
    dwconv_k<true><<<dim3(1024), 256, 0, stream>>>(
        x, qkv_dw, bn1_g, bn1_b, bn1_m, bn1_v, t);

    // 2. q = qkv_pw[0:256] * t     bf16 [B,256,4096]
    mgemm_k<0, true><<<dim3(32, 2, 8), 256, 0, stream>>>(
        t, qkv_pw, q, nullptr, nullptr, nullptr, nullptr, nullptr,
        4096, 256);

    // 3. tr = interp(t) -> 16x16
    interp_k<<<dim3(2048), 256, 0, stream>>>(t, tr);

    // 4. kv = qkv_pw[256:768] * tr   bf16 [B,512,256]
    mgemm_k<0, true><<<dim3(2, 4, 8), 256, 0, stream>>>(
        tr, qkv_pw + 256 * 256, kv, nullptr, nullptr, nullptr, nullptr, nullptr,
        256, 512);

    // 5. o = MFMA attention(q, kv, btab)   f32 [B,256,4096]  (overwrites t)
    attn_mfma_k<<<dim3(16, 8, 8), 256, 0, stream>>>(
        (const unsigned short*)q, (const unsigned short*)kv, btab, o);

    // 6. t2 = dwconv3(o)            (overwrites q)
    dwconv_k<false><<<dim3(1024), 256, 0, stream>>>(
        o, out_dw, nullptr, nullptr, nullptr, nullptr, t2);

    // 7. a = out_pw * t2 + x        (overwrites o)
    mgemm_k<1, false><<<dim3(32, 2, 8), 256, 0, stream>>>(
        t2, out_pw, a, x, nullptr, nullptr, nullptr, nullptr,
        4096, 256);

    // 8. out = mlp_w * relu(bn2(a)) + a
    mgemm_k<2, false><<<dim3(32, 2, 8), 256, 0, stream>>>(
        a, mlp_w, out, a, bn2_g, bn2_b, bn2_m, bn2_v,
        4096, 256);
}

// Round 7
// 146.677 us; speedup vs baseline: 1.5415x; 1.5415x over previous
//
#include <hip/hip_runtime.h>
#include <hip/hip_bf16.h>
#include <math.h>

#define EPSF 1e-5f

typedef float f32x4 __attribute__((ext_vector_type(4)));
typedef short short8 __attribute__((ext_vector_type(8)));
typedef short short4v __attribute__((ext_vector_type(4)));

static __device__ __forceinline__ unsigned short f2bf(float f) {
    unsigned u = __float_as_uint(f);
    u = (u + 0x7FFF + ((u >> 16) & 1)) >> 16;
    return (unsigned short)u;
}

static __device__ __forceinline__ unsigned packbf2(float a, float b) {
    __hip_bfloat162 t = __float22bfloat162_rn(float2{a, b});
    union { __hip_bfloat162 v; unsigned u; } cv;
    cv.v = t;
    return cv.u;
}

// XOR-swizzle: spreads 8-byte granules of a row across banks; keeps 16B pairs.
static __device__ __forceinline__ int swz(int r) { return ((r ^ (r >> 2)) & 7) << 1; }

// ---------------------------------------------------------------------------
// Depthwise 3x3 conv (SAME), vectorized: each thread computes a 4x8 tile.
// ---------------------------------------------------------------------------
template<bool BN>
__global__ __launch_bounds__(256) void dwconv_k(
    const float* __restrict__ X, const float* __restrict__ DW,
    const float* __restrict__ g, const float* __restrict__ be,
    const float* __restrict__ mn, const float* __restrict__ vr,
    float* __restrict__ Out)
{
    int tid = threadIdx.x;
    int plane = blockIdx.x * 2 + (tid >> 7);
    int c = plane & 255;
    float inv = 1.f, ad = 0.f;
    if (BN) {
        inv = g[c] * rsqrtf(vr[c] + EPSF);
        ad  = be[c] - mn[c] * inv;
    }
    float w[9];
#pragma unroll
    for (int i = 0; i < 9; ++i) w[i] = DW[c * 9 + i];
    const float* Xb = X + (size_t)plane * 4096;
    float* Ob = Out + (size_t)plane * 4096;
    int u  = tid & 127;
    int y0 = (u >> 3) * 4;
    int x0 = (u & 7) * 8;

    float r[6][16];
#pragma unroll
    for (int rr = 0; rr < 6; ++rr) {
        int yy = y0 + rr - 1;
        bool rv = (unsigned)yy < 64u;
#pragma unroll
        for (int gq = 0; gq < 4; ++gq) {
            int xx = x0 - 4 + gq * 4;
            f32x4 v = {0.f, 0.f, 0.f, 0.f};
            if (rv && (unsigned)xx < 64u) {
                v = *(const f32x4*)&Xb[yy * 64 + xx];
                if (BN) {
#pragma unroll
                    for (int j = 0; j < 4; ++j) v[j] = v[j] * inv + ad;
                }
            }
            r[rr][gq * 4 + 0] = v[0]; r[rr][gq * 4 + 1] = v[1];
            r[rr][gq * 4 + 2] = v[2]; r[rr][gq * 4 + 3] = v[3];
        }
    }

#pragma unroll
    for (int j = 0; j < 4; ++j) {
        float acc[8] = {};
#pragma unroll
        for (int ky = 0; ky < 3; ++ky) {
#pragma unroll
            for (int kx = 0; kx < 3; ++kx) {
                float ww = w[ky * 3 + kx];
#pragma unroll
                for (int p = 0; p < 8; ++p)
                    acc[p] += ww * r[j + ky][3 + p + kx];
            }
        }
        f32x4 lo = {acc[0], acc[1], acc[2], acc[3]};
        f32x4 hi = {acc[4], acc[5], acc[6], acc[7]};
        *(f32x4*)&Ob[(y0 + j) * 64 + x0]     = lo;
        *(f32x4*)&Ob[(y0 + j) * 64 + x0 + 4] = hi;
    }
}

// ---------------------------------------------------------------------------
// Bilinear align_corners=True resize 64x64 -> 16x16 per channel plane.
// ---------------------------------------------------------------------------
__global__ __launch_bounds__(256) void interp_k(
    const float* __restrict__ T, float* __restrict__ R)
{
    int bc = blockIdx.x;
    const float* Tb = T + (size_t)bc * 4096;
    int p  = threadIdx.x;
    int oy = p >> 4, ox = p & 15;
    const float st = 63.0f / 15.0f;
    float fy = oy * st, fx = ox * st;
    int y0 = (int)floorf(fy); int y1 = min(y0 + 1, 63); float wy = fy - (float)y0;
    int x0 = (int)floorf(fx); int x1 = min(x0 + 1, 63); float wx = fx - (float)x0;
    float v00 = Tb[y0 * 64 + x0], v01 = Tb[y0 * 64 + x1];
    float v10 = Tb[y1 * 64 + x0], v11 = Tb[y1 * 64 + x1];
    R[(size_t)bc * 256 + p] =
        (1.f - wy) * ((1.f - wx) * v00 + wx * v01) +
        wy         * ((1.f - wx) * v10 + wx * v11);
}

// ---------------------------------------------------------------------------
// Relative-position bias precompute: btab[h][qcell][key] (f32, 2 MB).
// ---------------------------------------------------------------------------
__global__ __launch_bounds__(256) void bias_k(
    const float* __restrict__ rel, float* __restrict__ btab)
{
    int idx = blockIdx.x * 256 + threadIdx.x;  // 524288 total
    int h   = idx >> 16;
    int qc  = (idx >> 8) & 255;
    int key = idx & 255;
    int ay = qc >> 4, ax = qc & 15, by = key >> 4, bx = key & 15;
    int t = (ay - by + 15) * 31 + (ax - bx + 15);
    btab[idx] = rel[t * 8 + h];
}

// ---------------------------------------------------------------------------
// bf16 MFMA GEMM: Out[b][n][m] = sum_k W[n][k] * A[b][k][m]  (K=256 fixed)
// MODE 0: plain. MODE 1: += X. MODE 2: A'=relu(bn(A)) (channel=k), += X.
// OB: write output as bf16 (ushort) instead of f32.
// ---------------------------------------------------------------------------
template<int MODE, bool OB>
__global__ __launch_bounds__(256) void mgemm_k(
    const float* __restrict__ A, const float* __restrict__ W,
    float* __restrict__ Out, const float* __restrict__ X,
    const float* __restrict__ g, const float* __restrict__ be,
    const float* __restrict__ mn, const float* __restrict__ vr,
    int M, int Ntot)
{
    __shared__ short Ws[128 * 256];
    __shared__ short As[128 * 64];
    int b = blockIdx.z, m0 = blockIdx.x * 128, n0 = blockIdx.y * 128;
    int tid = threadIdx.x;
    const float* Ab = A + (size_t)b * 256 * M;

#pragma unroll
    for (int it = 0; it < 32; ++it) {
        int idx = it * 256 + tid;
        int n = idx >> 6, kq = idx & 63;
        f32x4 w4 = *(const f32x4*)&W[(size_t)(n0 + n) * 256 + kq * 4];
        short4v pk = { (short)f2bf(w4[0]), (short)f2bf(w4[1]),
                       (short)f2bf(w4[2]), (short)f2bf(w4[3]) };
        *(short4v*)&Ws[n * 256 + ((kq ^ swz(n)) << 2)] = pk;
    }

    int mg = tid & 31, kg = tid >> 5;
    f32x4 rg[8];
    auto load_tile = [&](int k0) {
#pragma unroll
        for (int half = 0; half < 2; ++half) {
#pragma unroll
            for (int i = 0; i < 4; ++i) {
                int c = k0 + kg * 4 + half * 32 + i;
                f32x4 v = *(const f32x4*)&Ab[(size_t)c * M + m0 + mg * 4];
                if (MODE == 2) {
                    float iv = g[c] * rsqrtf(vr[c] + EPSF);
                    float ad = be[c] - mn[c] * iv;
#pragma unroll
                    for (int j = 0; j < 4; ++j) v[j] = fmaxf(v[j] * iv + ad, 0.f);
                }
                rg[half * 4 + i] = v;
            }
        }
    };
    load_tile(0);

    int w = tid >> 6, lane = tid & 63;
    int wm = w & 1, wn = w >> 1;
    int lg = lane >> 4, lc = lane & 15;
    f32x4 acc[4][4] = {};

    for (int k0 = 0; k0 < 256; k0 += 64) {
        __syncthreads();
#pragma unroll
        for (int half = 0; half < 2; ++half) {
#pragma unroll
            for (int j = 0; j < 4; ++j) {
                int m = mg * 4 + j;
                short4v pk = { (short)f2bf(rg[half * 4 + 0][j]), (short)f2bf(rg[half * 4 + 1][j]),
                               (short)f2bf(rg[half * 4 + 2][j]), (short)f2bf(rg[half * 4 + 3][j]) };
                *(short4v*)&As[m * 64 + (((kg + half * 8) ^ swz(m)) << 2)] = pk;
            }
        }
        __syncthreads();
        if (k0 < 192) load_tile(k0 + 64);
#pragma unroll
        for (int ksl = 0; ksl < 2; ++ksl) {
            short8 wf[4], af[4];
            int gk = (k0 + ksl * 32 + lg * 8) >> 2;
            int ga = (ksl * 32 + lg * 8) >> 2;
#pragma unroll
            for (int nt = 0; nt < 4; ++nt) {
                int n = wn * 64 + nt * 16 + lc;
                wf[nt] = *(const short8*)&Ws[n * 256 + ((gk ^ swz(n)) << 2)];
            }
#pragma unroll
            for (int mt = 0; mt < 4; ++mt) {
                int m = wm * 64 + mt * 16 + lc;
                af[mt] = *(const short8*)&As[m * 64 + ((ga ^ swz(m)) << 2)];
            }
#pragma unroll
            for (int nt = 0; nt < 4; ++nt)
#pragma unroll
                for (int mt = 0; mt < 4; ++mt)
                    acc[nt][mt] = __builtin_amdgcn_mfma_f32_16x16x32_bf16(
                        wf[nt], af[mt], acc[nt][mt], 0, 0, 0);
        }
    }

    size_t ob = (size_t)b * Ntot * M;
#pragma unroll
    for (int nt = 0; nt < 4; ++nt) {
#pragma unroll
        for (int mt = 0; mt < 4; ++mt) {
#pragma unroll
            for (int reg = 0; reg < 4; ++reg) {
                int n = n0 + wn * 64 + nt * 16 + lg * 4 + reg;
                int m = m0 + wm * 64 + mt * 16 + lc;
                size_t addr = ob + (size_t)n * M + m;
                float v = acc[nt][mt][reg];
                if (MODE >= 1) v += X[addr];
                if (OB) ((unsigned short*)Out)[addr] = f2bf(v);
                else    Out[addr] = v;
            }
        }
    }
}

// ---------------------------------------------------------------------------
// MFMA attention, swapped-QK layout: S[key][qrow].
// Bias comes in as mfma C-init from global btab (L2). No rels LDS, no P LDS.
// grid (16, H, B), 256 threads = 4 waves, each wave 64 q-rows (4 m-tiles).
// launch_bounds (256,2): min 2 waves/EU -> VGPR cap 256 (NO spills; the
// (256,4) variant clamped VGPR to 64 and spilled ~100 MB to scratch).
// ---------------------------------------------------------------------------
__global__ __launch_bounds__(256, 2) void attn_mfma_k(
    const unsigned short* __restrict__ Q, const unsigned short* __restrict__ KV,
    const float* __restrict__ btab, float* __restrict__ O)
{
    __shared__ unsigned short Ks[256 * 40];   // [key][dim], pad 40 (20.0 KB)
    __shared__ unsigned short Vt[32 * 264];   // [dim][key], pad 264 (16.9 KB)

    int b = blockIdx.z, h = blockIdx.y, chunk = blockIdx.x;
    int tid = threadIdx.x;
    const unsigned short* kvb = KV + (size_t)b * 512 * 256;

    // stage K: Ks[key][dim] (pairs of dims -> b32 writes)
#pragma unroll
    for (int it = 0; it < 16; ++it) {
        int idx = it * 256 + tid;
        int r = idx & 255, d = (idx >> 8) * 2;
        unsigned pk = (unsigned)kvb[(size_t)(d * 8 + h) * 256 + r]
                    | ((unsigned)kvb[(size_t)((d + 1) * 8 + h) * 256 + r] << 16);
        *(unsigned*)&Ks[r * 40 + d] = pk;
    }
    // stage V transposed: Vt[dim][key] (4 consecutive keys -> b64 writes)
#pragma unroll
    for (int it = 0; it < 8; ++it) {
        int idx = it * 256 + tid;
        int d = idx >> 6, k4 = (idx & 63) * 4;
        ushort4 v4 = *(const ushort4*)&kvb[(size_t)(256 + d * 8 + h) * 256 + k4];
        *(ushort4*)&Vt[d * 264 + k4] = v4;
    }
    __syncthreads();

    int w = tid >> 6, lane = tid & 63;
    int lg = lane >> 4, lc = lane & 15;

    const float SCALE = 0.17677669529663687f;  // 32^-0.5
    const unsigned short* Qb = Q + (size_t)b * 256 * 4096;
    float* Ob = O + (size_t)b * 256 * 4096;
    const float* bt = btab + (size_t)h * 256 * 256;
    int rw = chunk * 256 + w * 64;

    int s1 = ((lg & 1) << 5) + lc;
    int s2 = s1 + 16;
    bool useOdd = (lg >> 1) != 0;

    for (int mt = 0; mt < 4; ++mt) {
        int rbase = rw + mt * 16;
        int r_a = rbase + lc;
        int qc = ((r_a >> 8) << 4) | ((r_a >> 2) & 15);
        const float* bq = bt + (size_t)qc * 256 + lg * 4;

        // bias into accumulator (C-init)
        f32x4 sacc[16];
#pragma unroll
        for (int kt = 0; kt < 16; ++kt)
            sacc[kt] = *(const f32x4*)&bq[kt * 16];

        // Q B-fragment: col = qrow (lc), k = dim lg*8+j
        short8 qf;
#pragma unroll
        for (int j = 0; j < 8; ++j)
            qf[j] = (short)Qb[(size_t)((lg * 8 + j) * 8 + h) * 4096 + r_a];

        // QK^T swapped with bias C-init: sacc = K·Q + bias
#pragma unroll
        for (int kt = 0; kt < 16; ++kt) {
            short8 kf = *(const short8*)&Ks[(kt * 16 + lc) * 40 + lg * 8];
            sacc[kt] = __builtin_amdgcn_mfma_f32_16x16x32_bf16(kf, qf, sacc[kt], 0, 0, 0);
        }

        // raw row max (row = q-row = lc, across lg,kt,reg)
        float mx = -1e30f;
#pragma unroll
        for (int kt = 0; kt < 16; ++kt)
            mx = fmaxf(mx, fmaxf(fmaxf(sacc[kt][0], sacc[kt][1]),
                                 fmaxf(sacc[kt][2], sacc[kt][3])));
        mx = fmaxf(mx, __shfl_xor(mx, 16));
        mx = fmaxf(mx, __shfl_xor(mx, 32));
        float nms = -mx * SCALE;

        // fused exp + pack + exchange + PV
        float ls = 0.f;
        f32x4 o0 = {0.f, 0.f, 0.f, 0.f}, o1 = {0.f, 0.f, 0.f, 0.f};
#pragma unroll
        for (int ks = 0; ks < 8; ++ks) {
            float pa0 = __expf(fmaf(sacc[2 * ks][0],     SCALE, nms));
            float pa1 = __expf(fmaf(sacc[2 * ks][1],     SCALE, nms));
            float pa2 = __expf(fmaf(sacc[2 * ks][2],     SCALE, nms));
            float pa3 = __expf(fmaf(sacc[2 * ks][3],     SCALE, nms));
            float pb0 = __expf(fmaf(sacc[2 * ks + 1][0], SCALE, nms));
            float pb1 = __expf(fmaf(sacc[2 * ks + 1][1], SCALE, nms));
            float pb2 = __expf(fmaf(sacc[2 * ks + 1][2], SCALE, nms));
            float pb3 = __expf(fmaf(sacc[2 * ks + 1][3], SCALE, nms));
            ls += ((pa0 + pa1) + (pa2 + pa3)) + ((pb0 + pb1) + (pb2 + pb3));
            unsigned pl0 = packbf2(pa0, pa1), ph0 = packbf2(pa2, pa3);
            unsigned pl1 = packbf2(pb0, pb1), ph1 = packbf2(pb2, pb3);

            int eA = __shfl((int)pl0, s1), oA = __shfl((int)pl1, s1);
            int eB = __shfl((int)ph0, s1), oB = __shfl((int)ph1, s1);
            int eC = __shfl((int)pl0, s2), oC = __shfl((int)pl1, s2);
            int eD = __shfl((int)ph0, s2), oD = __shfl((int)ph1, s2);
            int4 pi = { useOdd ? oA : eA, useOdd ? oB : eB,
                        useOdd ? oC : eC, useOdd ? oD : eD };
            short8 pf = *(short8*)&pi;
            short8 v0 = *(const short8*)&Vt[lc * 264 + ks * 32 + lg * 8];
            short8 v1 = *(const short8*)&Vt[(16 + lc) * 264 + ks * 32 + lg * 8];
            o0 = __builtin_amdgcn_mfma_f32_16x16x32_bf16(v0, pf, o0, 0, 0, 0);
            o1 = __builtin_amdgcn_mfma_f32_16x16x32_bf16(v1, pf, o1, 0, 0, 0);
        }
        ls += __shfl_xor(ls, 16);
        ls += __shfl_xor(ls, 32);

        // epilogue: lane holds dims d=lg*4+reg (o0) / 16+lg*4+reg (o1), qrow=lc
        float rl = 1.f / ls;
#pragma unroll
        for (int reg = 0; reg < 4; ++reg) {
            int d0 = lg * 4 + reg;
            Ob[(size_t)(d0 * 8 + h) * 4096 + rbase + lc]        = o0[reg] * rl;
            Ob[(size_t)((16 + d0) * 8 + h) * 4096 + rbase + lc] = o1[reg] * rl;
        }
    }
}

// ---------------------------------------------------------------------------
extern "C" void kernel_launch(void* const* d_in, const int* in_sizes, int n_in,
                              void* d_out, int out_size, void* d_ws, size_t ws_size,
                              hipStream_t stream)
{
    const float* x       = (const float*)d_in[0];
    const float* bn1_g   = (const float*)d_in[1];
    const float* bn1_b   = (const float*)d_in[2];
    const float* bn1_m   = (const float*)d_in[3];
    const float* bn1_v   = (const float*)d_in[4];
    const float* qkv_dw  = (const float*)d_in[5];
    const float* qkv_pw  = (const float*)d_in[6];
    const float* out_dw  = (const float*)d_in[7];
    const float* out_pw  = (const float*)d_in[8];
    const float* rel     = (const float*)d_in[9];
    const float* bn2_g   = (const float*)d_in[10];
    const float* bn2_b   = (const float*)d_in[11];
    const float* bn2_m   = (const float*)d_in[12];
    const float* bn2_v   = (const float*)d_in[13];
    const float* mlp_w   = (const float*)d_in[14];
    float* out = (float*)d_out;

    float* ws = (float*)d_ws;
    float* t    = ws;                            // BUF0: t / o / a (f32)
    float* q    = ws + (size_t)8 * 1024 * 1024;  // BUF1: q(bf16) / t2(f32)
    float* tr   = ws + (size_t)16 * 1024 * 1024;
    float* kv   = tr + 524288;                   // bf16 region (2 MB used)
    float* btab = kv + 1048576;                  // f32 bias table (2 MB)
    float* o   = t;
    float* t2  = q;
    float* a   = t;

    // 0. bias table precompute
    bias_k<<<dim3(2048), 256, 0, stream>>>(rel, btab);

    // 1. t = dwconv3(bn1(x))
    dwconv_k<true><<<dim3(1024), 256, 0, stream>>>(
        x, qkv_dw, bn1_g, bn1_b, bn1_m, bn1_v, t);

    // 2. q = qkv_pw[0:256] * t     bf16 [B,256,4096]
    mgemm_k<0, true><<<dim3(32, 2, 8), 256, 0, stream>>>(
        t, qkv_pw, q, nullptr, nullptr, nullptr, nullptr, nullptr,
        4096, 256);

    // 3. tr = interp(t) -> 16x16
    interp_k<<<dim3(2048), 256, 0, stream>>>(t, tr);

    // 4. kv = qkv_pw[256:768] * tr   bf16 [B,512,256]
    mgemm_k<0, true><<<dim3(2, 4, 8), 256, 0, stream>>>(
        tr, qkv_pw + 256 * 256, kv, nullptr, nullptr, nullptr, nullptr, nullptr,
        256, 512);

    // 5. o = MFMA attention(q, kv, btab)   f32 [B,256,4096]  (overwrites t)
    attn_mfma_k<<<dim3(16, 8, 8), 256, 0, stream>>>(
        (const unsigned short*)q, (const unsigned short*)kv, btab, o);

    // 6. t2 = dwconv3(o)            (overwrites q)
    dwconv_k<false><<<dim3(1024), 256, 0, stream>>>(
        o, out_dw, nullptr, nullptr, nullptr, nullptr, t2);

    // 7. a = out_pw * t2 + x        (overwrites o)
    mgemm_k<1, false><<<dim3(32, 2, 8), 256, 0, stream>>>(
        t2, out_pw, a, x, nullptr, nullptr, nullptr, nullptr,
        4096, 256);

    // 8. out = mlp_w * relu(bn2(a)) + a
    mgemm_k<2, false><<<dim3(32, 2, 8), 256, 0, stream>>>(
        a, mlp_w, out, a, bn2_g, bn2_b, bn2_m, bn2_v,
        4096, 256);
}